// Round 11
// baseline (48.530 us; speedup 1.0000x reference)
//
#include <hip/hip_runtime.h>
#include <math.h>

#define NB 16
#define NC 256
#define NH 64
#define NW 64
#define HALF 128
#define PLANE (NH*NW)   // 4096

#define NT 4                  // tiles per block (4 channel pairs each)
#define S_UNIT 260            // floats per staged unit (1024B data + 16B pad)
#define TILEF (32*S_UNIT)     // 8320 floats per tile buffer

// ws: attention map only
#define WS_ATT 0              // NB*NH*NW = 65536 floats

// d_out scratch (floats): 8 cons slices + gh partials + gw partials
#define SCR_GHP 524288              // [b*64+h]*8 + pgc          : 8192 floats
#define SCR_GWP (SCR_GHP + 8192)    // [b*64+w]*32 + (pgc*4+st)  : 32768 floats

typedef __attribute__((address_space(1))) void gvoid;
typedef __attribute__((address_space(3))) void lvoid;

// async global->LDS, 16B/lane; global src per-lane, LDS dest uniform+lane*16
__device__ __forceinline__ void async_load16(const float* g, float* l) {
    __builtin_amdgcn_global_load_lds((gvoid*)(size_t)(const void*)g, (lvoid*)l, 16, 0, 0);
}

__device__ __forceinline__ float sum4(float4 v) { return (v.x+v.y)+(v.z+v.w); }

// Block = (b, 16-row stripe, chunk of NT=4 pair-groups). 512 blocks (2/CU).
// Wave rg owns rows r0..r0+3; lane = fc(4b)<<2 | pl(2b).
// Staging: CONTIGUOUS units (1 channel x 4 rows = 1KB dense), 8 per wave per
// tile; stripe-halo rows via 2 register float4 loads on edge waves (counted:
// vmcnt(10) edge / vmcnt(8) middle). Pipelined double buffer, plain-store
// epilogue (no atomics). Softmax in-prologue.
__global__ __launch_bounds__(256) void k_reduce(const float* __restrict__ x,
                                                const float* __restrict__ dwh,
                                                const float* __restrict__ dww,
                                                float* __restrict__ scr) {
    __shared__ float stage[2*TILEF];          // ~66.6 KB double buffer
    __shared__ float ew[256], eh[256];        // exp(weights)
    __shared__ float wsum[8];                 // wave partial sums (w:0-3, h:4-7)
    __shared__ float4 ldsc[4][16];            // gw cross-wave staging

    const int t    = threadIdx.x;
    const int rg   = t >> 6;       // wave = row group 0..3
    const int lane = t & 63;
    const int pl   = lane & 3;     // channel-pair lane
    const int fc   = lane >> 2;    // float4 col 0..15

    const int blk    = blockIdx.x;
    const int pgc    = blk & 7;          // pair-group chunk 0..7
    const int stripe = (blk >> 3) & 3;
    const int b      = blk >> 5;
    const int r0s    = stripe * 16;
    const int r0     = r0s + rg*4;       // first owned row

    const bool edge = (rg == 0) || (rg == 3);
    const size_t bbase = (size_t)b * NC * PLANE;

    // ---- prologue: exp(weights) + wave partial sums into LDS
    {
        const float vw = dww[t], vh = dwh[t];
        const float evw = expf(vw), evh = expf(vh);
        ew[t] = evw; eh[t] = evh;
        float sw = evw, sh = evh;
        #pragma unroll
        for (int m = 1; m < 64; m <<= 1) { sw += __shfl_xor(sw, m); sh += __shfl_xor(sh, m); }
        if (lane == 0) { wsum[rg] = sw; wsum[4+rg] = sh; }
    }
    asm volatile("s_waitcnt vmcnt(0) lgkmcnt(0)" ::: "memory");  // reset counting

    // ---- staging helpers (tk is always a compile-time literal at call sites)
    auto issue_tile = [&](int tk) {
        const int pg = pgc*NT + tk;
        float* dstb = &stage[(tk & 1) * TILEF];
        #pragma unroll
        for (int i = 0; i < 8; ++i) {
            const int u   = rg*8 + i;
            const int chh = u >> 2;            // 0..7
            const int rq  = u & 3;
            const int cg  = pg*4 + (chh & 3) + (chh >> 2)*HALF;
            const float* src = x + bbase + (size_t)cg*PLANE + (size_t)(r0s + rq*4)*NW + lane*4;
            async_load16(src, dstb + u*S_UNIT);
        }
    };
    auto load_halo = [&](int tk, float4& ha, float4& hb) {
        if (edge) {                               // wave-uniform branch
            int hr = (rg == 0) ? r0s - 1 : r0s + 16;
            hr = hr < 0 ? 0 : (hr > 63 ? 63 : hr);
            const int c1 = (pgc*NT + tk)*4 + pl;
            ha = *reinterpret_cast<const float4*>(x + bbase + (size_t)c1*PLANE + hr*NW + fc*4);
            hb = *reinterpret_cast<const float4*>(x + bbase + (size_t)(c1+HALF)*PLANE + hr*NW + fc*4);
        }
    };

    const float km0 = (r0 == 0)  ? 0.f : 1.f;
    const float km5 = (r0 == 60) ? 0.f : 1.f;
    float invSw = 0.f, invSh = 0.f;
    float4 c4[4] = {{0,0,0,0},{0,0,0,0},{0,0,0,0},{0,0,0,0}};
    float  ghrow[4] = {0.f,0.f,0.f,0.f};
    float4 colacc = {0.f,0.f,0.f,0.f};

    float4 haA = {0,0,0,0}, hbA = {0,0,0,0};   // halo for even tiles
    float4 haB = {0,0,0,0}, hbB = {0,0,0,0};   // halo for odd tiles

    // ---- issue tile 0 (+ halo 0)
    issue_tile(0);
    load_halo(0, haA, hbA);

    auto tile_iter = [&](int tk, const float4& haU, const float4& hbU,
                         float4& haL, float4& hbL) {
        asm volatile("s_waitcnt lgkmcnt(0)" ::: "memory");  // my ds reads done
        __builtin_amdgcn_s_barrier();          // all waves done with buf[(tk+1)&1]

        if (tk == 0) {
            invSw = 1.f / ((wsum[0]+wsum[1]) + (wsum[2]+wsum[3]));
            invSh = 1.f / ((wsum[4]+wsum[5]) + (wsum[6]+wsum[7]));
        }
        if (tk < NT-1) {
            issue_tile(tk + 1);
            load_halo(tk + 1, haL, hbL);
            if (edge) asm volatile("s_waitcnt vmcnt(10)" ::: "memory");
            else      asm volatile("s_waitcnt vmcnt(8)"  ::: "memory");
        } else {
            asm volatile("s_waitcnt vmcnt(0)" ::: "memory");
        }
        __builtin_amdgcn_s_barrier();          // tile tk fully staged

        // ---- compute tile tk
        const int pg = pgc*NT + tk;
        const float ww1 = ew[pg*4+pl]      * invSw;
        const float ww2 = ew[pg*4+pl+HALF] * invSw;
        const float wh1 = eh[pg*4+pl]      * invSh;
        const float wh2 = eh[pg*4+pl+HALF] * invSh;

        const float* buf = &stage[(tk & 1) * TILEF];
        float4 a[6], bv[6];
        #pragma unroll
        for (int j = 0; j < 6; ++j) {
            const int lr = rg*4 - 1 + j;                 // -1..16
            if (j == 0 && rg == 0) { a[j] = haU; bv[j] = hbU; }
            else if (j == 5 && rg == 3) { a[j] = haU; bv[j] = hbU; }
            else {
                const int uA  = pl*4 + (lr >> 2);
                const int off = (lr & 3)*64 + fc*4;
                a[j]  = *reinterpret_cast<const float4*>(buf + uA*S_UNIT + off);
                bv[j] = *reinterpret_cast<const float4*>(buf + (uA+16)*S_UNIT + off);
            }
        }

        #pragma unroll
        for (int j = 1; j <= 4; ++j) {
            ghrow[j-1] += ww1*sum4(a[j]) + ww2*sum4(bv[j]);
            colacc.x += wh1*a[j].x + wh2*bv[j].x;
            colacc.y += wh1*a[j].y + wh2*bv[j].y;
            colacc.z += wh1*a[j].z + wh2*bv[j].z;
            colacc.w += wh1*a[j].w + wh2*bv[j].w;
        }

        float4 p[6];
        #pragma unroll
        for (int j = 0; j < 6; ++j) {
            p[j].x = a[j].x*bv[j].x; p[j].y = a[j].y*bv[j].y;
            p[j].z = a[j].z*bv[j].z; p[j].w = a[j].w*bv[j].w;
        }
        p[0].x *= km0; p[0].y *= km0; p[0].z *= km0; p[0].w *= km0;
        p[5].x *= km5; p[5].y *= km5; p[5].z *= km5; p[5].w *= km5;

        #pragma unroll
        for (int i = 0; i < 4; ++i) {
            float4 v;
            v.x = p[i].x + p[i+1].x + p[i+2].x;
            v.y = p[i].y + p[i+1].y + p[i+2].y;
            v.z = p[i].z + p[i+1].z + p[i+2].z;
            v.w = p[i].w + p[i+1].w + p[i+2].w;
            float L = __shfl_up(v.w, 4);
            float R = __shfl_down(v.x, 4);
            if (fc == 0)  L = 0.f;
            if (fc == 15) R = 0.f;
            c4[i].x += fabsf(L   + v.x + v.y);
            c4[i].y += fabsf(v.x + v.y + v.z);
            c4[i].z += fabsf(v.y + v.z + v.w);
            c4[i].w += fabsf(v.z + v.w + R);
        }
    };

    tile_iter(0, haA, hbA, haB, hbB);
    tile_iter(1, haB, hbB, haA, hbA);
    tile_iter(2, haA, hbA, haB, hbB);
    tile_iter(3, haB, hbB, haA, hbA);

    // ---- epilogue (plain stores, no atomics)
    const float SC  = 1.0f/(9.0f*128.0f);
    const float GSC = 1.0f/16384.0f;

    // cons: reduce over 4 pair-lanes -> slice pgc store
    #pragma unroll
    for (int i = 0; i < 4; ++i) {
        c4[i].x += __shfl_xor(c4[i].x, 1); c4[i].x += __shfl_xor(c4[i].x, 2);
        c4[i].y += __shfl_xor(c4[i].y, 1); c4[i].y += __shfl_xor(c4[i].y, 2);
        c4[i].z += __shfl_xor(c4[i].z, 1); c4[i].z += __shfl_xor(c4[i].z, 2);
        c4[i].w += __shfl_xor(c4[i].w, 1); c4[i].w += __shfl_xor(c4[i].w, 2);
    }
    if (pl == 0) {
        float4* dst = reinterpret_cast<float4*>(scr) + (pgc << 14) + (b << 10);
        #pragma unroll
        for (int i = 0; i < 4; ++i) {
            float4 s = { c4[i].x*SC, c4[i].y*SC, c4[i].z*SC, c4[i].w*SC };
            dst[(r0 + i)*16 + fc] = s;
        }
    }

    // gh: full-wave reduce per owned row (complete over this chunk)
    #pragma unroll
    for (int i = 0; i < 4; ++i) {
        float s = ghrow[i];
        s += __shfl_xor(s, 1);  s += __shfl_xor(s, 2);
        s += __shfl_xor(s, 4);  s += __shfl_xor(s, 8);
        s += __shfl_xor(s, 16); s += __shfl_xor(s, 32);
        if (lane == 0) scr[SCR_GHP + (b*NH + r0 + i)*8 + pgc] = s * GSC;
    }

    // gw: reduce over pairs (shfl), stage per wave, store TRANSPOSED [b][w][32]
    colacc.x += __shfl_xor(colacc.x, 1); colacc.x += __shfl_xor(colacc.x, 2);
    colacc.y += __shfl_xor(colacc.y, 1); colacc.y += __shfl_xor(colacc.y, 2);
    colacc.z += __shfl_xor(colacc.z, 1); colacc.z += __shfl_xor(colacc.z, 2);
    colacc.w += __shfl_xor(colacc.w, 1); colacc.w += __shfl_xor(colacc.w, 2);
    if (pl == 0) ldsc[rg][fc] = colacc;
    __syncthreads();
    if (t < 64) {
        const float* lf = reinterpret_cast<const float*>(ldsc);  // flat [g*64 + w]
        float s = (lf[t] + lf[64+t]) + (lf[128+t] + lf[192+t]);
        scr[SCR_GWP + (b*NW + t)*32 + pgc*4 + stripe] = s * GSC;
    }
}

// 64 blocks (b, quarter): vectorized gh/gw partial reduction, sum 8 cons
// slices, sigmoid -> att map in ws.
__global__ __launch_bounds__(256) void k_att(float* __restrict__ ws,
                                             const float* __restrict__ scr,
                                             const float* __restrict__ pgw,
                                             const float* __restrict__ pgb) {
    __shared__ __align__(16) float sgh[64];
    __shared__ __align__(16) float sgw[64];
    const int t = threadIdx.x;
    const int b = blockIdx.x >> 2;
    const int q = blockIdx.x & 3;

    if (t < 64) {
        const float4* gp = reinterpret_cast<const float4*>(scr + SCR_GWP + (b*NW + t)*32);
        float acc = ((sum4(gp[0])+sum4(gp[1])) + (sum4(gp[2])+sum4(gp[3])))
                  + ((sum4(gp[4])+sum4(gp[5])) + (sum4(gp[6])+sum4(gp[7])));
        sgw[t] = acc;
    } else if (t < 128) {
        const int r = t - 64;
        const float4* gp = reinterpret_cast<const float4*>(scr + SCR_GHP + (b*NH + r)*8);
        sgh[r] = sum4(gp[0]) + sum4(gp[1]);
    }
    __syncthreads();

    const int u = (b << 10) + (q << 8) + t;   // float4-pixel 0..16383
    const float4* cp = reinterpret_cast<const float4*>(scr);
    float4 s = {0.f,0.f,0.f,0.f};
    #pragma unroll
    for (int g = 0; g < 8; ++g) {
        const float4 v = cp[(g << 14) + u];
        s.x += v.x; s.y += v.y; s.z += v.z; s.w += v.w;
    }
    const int h  = (u >> 4) & 63;
    const int w4 = u & 15;
    const float ghv  = sgh[h];
    const float4 gwv = *reinterpret_cast<const float4*>(&sgw[w4*4]);
    const float gW = pgw[0], gB = pgb[0];

    float4 o;
    float z;
    z = gW*(ghv+gwv.x)*(1.f - fminf(fmaxf(s.x,0.f),1.f)) + gB; o.x = 1.f/(1.f+expf(-z));
    z = gW*(ghv+gwv.y)*(1.f - fminf(fmaxf(s.y,0.f),1.f)) + gB; o.y = 1.f/(1.f+expf(-z));
    z = gW*(ghv+gwv.z)*(1.f - fminf(fmaxf(s.z,0.f),1.f)) + gB; o.z = 1.f/(1.f+expf(-z));
    z = gW*(ghv+gwv.w)*(1.f - fminf(fmaxf(s.w,0.f),1.f)) + gB; o.w = 1.f/(1.f+expf(-z));
    reinterpret_cast<float4*>(ws + WS_ATT)[u] = o;
}

__global__ __launch_bounds__(256) void k_apply(const float* __restrict__ x,
                                               const float* __restrict__ ws,
                                               float* __restrict__ out) {
    const float* att = ws + WS_ATT;
    const int total4 = NB*NC*NH*NW/4;   // 4,194,304
    const int stride = gridDim.x * blockDim.x;
    for (int i = blockIdx.x*blockDim.x + threadIdx.x; i < total4; i += stride) {
        const int w4 = i & 15;
        const int h  = (i >> 4) & 63;
        const int b  = i >> 18;
        const float4 xv = reinterpret_cast<const float4*>(x)[i];
        const float4 av = reinterpret_cast<const float4*>(att)[(b << 10) + (h << 4) + w4];
        float4 o;
        o.x = xv.x*av.x; o.y = xv.y*av.y; o.z = xv.z*av.z; o.w = xv.w*av.w;
        reinterpret_cast<float4*>(out)[i] = o;
    }
}

extern "C" void kernel_launch(void* const* d_in, const int* in_sizes, int n_in,
                              void* d_out, int out_size, void* d_ws, size_t ws_size,
                              hipStream_t stream) {
    const float* x   = (const float*)d_in[0];
    const float* dwh = (const float*)d_in[1];
    const float* dww = (const float*)d_in[2];
    const float* pgw = (const float*)d_in[3];
    const float* pgb = (const float*)d_in[4];
    float* out = (float*)d_out;
    float* ws  = (float*)d_ws;
    // d_out doubles as scratch for reduce partials (~2.3 MB): written by
    // k_reduce, consumed by k_att, then fully overwritten by k_apply.
    float* scr = out;

    k_reduce<<<NB*4*8, 256, 0, stream>>>(x, dwh, dww, scr);
    k_att<<<64, 256, 0, stream>>>(ws, scr, pgw, pgb);
    k_apply<<<2048, 256, 0, stream>>>(x, ws, out);
}

// Round 12
// 44.031 us; speedup vs baseline: 1.1022x; 1.1022x over previous
//
#include <hip/hip_runtime.h>
#include <math.h>

#define NB 16
#define NC 256
#define NH 64
#define NW 64
#define HALF 128
#define PLANE (NH*NW)   // 4096

// ws: attention map only
#define WS_ATT 0              // NB*NH*NW = 65536 floats

// d_out scratch (floats), all plain stores:
#define SCR_CONS 0                   // 8 slices x [b][h][w] = 524288 floats
#define SCR_GHP  524288              // [b*64+h]*8 + cg : 8192 floats
#define SCR_GWP  (524288 + 8192)     // [b*64+w]*64 + cg*8+hg : 65536 floats

__device__ __forceinline__ float sum4(float4 v) { return (v.x+v.y)+(v.z+v.w); }

// Block = (b, cg: 16 channel-pairs, hg: 8-row stripe). 1024 blocks = 4/CU,
// 16 waves/CU. Wave v covers pairs cg*16+v*4..+3; lane = w4(4b)<<2 | pl(2b).
// k_apply-style streaming: per thread a 10-iteration row loop with 2
// independent float4 loads/iter, rolling 3-row product window in named regs,
// horizontal 3-tap via lane shuffles, pair-reduce via shfl_xor. ONE barrier
// (epilogue). Plain-store partials, zero atomics. Softmax in-prologue.
__global__ __launch_bounds__(256) void k_reduce(const float* __restrict__ x,
                                                const float* __restrict__ dwh,
                                                const float* __restrict__ dww,
                                                float* __restrict__ scr) {
    __shared__ float  ew[256], eh[256];       // exp(weights)
    __shared__ float  wsum[8];
    __shared__ float4 consacc[4][8][16];      // per-wave cons rows, 8 KB
    __shared__ float  ghacc[4][8];
    __shared__ float  gwacc[4][64];

    const int t    = threadIdx.x;
    const int v    = t >> 6;        // wave 0..3
    const int lane = t & 63;
    const int pl   = lane & 3;      // channel-pair lane
    const int w4   = lane >> 2;     // float4 col 0..15

    const int blk = blockIdx.x;
    const int hg  = blk & 7;            // 8-row stripe
    const int cg  = (blk >> 3) & 7;     // 16-pair group
    const int b   = blk >> 6;
    const int r0  = hg << 3;            // first owned row

    // ---- prologue: softmax denominators
    {
        const float vw = dww[t], vh = dwh[t];
        const float evw = expf(vw), evh = expf(vh);
        ew[t] = evw; eh[t] = evh;
        float sw = evw, sh = evh;
        #pragma unroll
        for (int m = 1; m < 64; m <<= 1) { sw += __shfl_xor(sw, m); sh += __shfl_xor(sh, m); }
        if (lane == 0) { wsum[v] = sw; wsum[4+v] = sh; }
    }
    __syncthreads();
    const float invSw = 1.f/((wsum[0]+wsum[1])+(wsum[2]+wsum[3]));
    const float invSh = 1.f/((wsum[4]+wsum[5])+(wsum[6]+wsum[7]));

    const int   c1  = cg*16 + v*4 + pl;
    const float ww1 = ew[c1]*invSw, ww2 = ew[c1+HALF]*invSw;
    const float wh1 = eh[c1]*invSh, wh2 = eh[c1+HALF]*invSh;

    const float* p1 = x + ((size_t)(b*NC + c1))*PLANE + w4*4;
    const float* p2 = p1 + (size_t)HALF*PLANE;

    // rolling product window (named regs -> no scratch)
    float4 w0 = {0,0,0,0}, w1 = {0,0,0,0}, w2 = {0,0,0,0};
    float4 colacc = {0,0,0,0};

    #pragma unroll
    for (int j = 0; j < 10; ++j) {
        const int r = r0 - 1 + j;                   // row to load
        float4 p = {0.f,0.f,0.f,0.f};
        const bool live = (j == 0) ? (r >= 0) : ((j == 9) ? (r < 64) : true);
        if (live) {
            const float4 x1 = *reinterpret_cast<const float4*>(p1 + r*NW);
            const float4 x2 = *reinterpret_cast<const float4*>(p2 + r*NW);
            p.x = x1.x*x2.x; p.y = x1.y*x2.y; p.z = x1.z*x2.z; p.w = x1.w*x2.w;
            if (j >= 1 && j <= 8) {                 // owned rows: gh/gw
                float g = ww1*sum4(x1) + ww2*sum4(x2);
                g += __shfl_xor(g,1);  g += __shfl_xor(g,2);  g += __shfl_xor(g,4);
                g += __shfl_xor(g,8);  g += __shfl_xor(g,16); g += __shfl_xor(g,32);
                if (lane == 0) ghacc[v][j-1] = g;
                colacc.x += wh1*x1.x + wh2*x2.x;
                colacc.y += wh1*x1.y + wh2*x2.y;
                colacc.z += wh1*x1.z + wh2*x2.z;
                colacc.w += wh1*x1.w + wh2*x2.w;
            }
        }
        w0 = w1; w1 = w2; w2 = p;
        if (j >= 2) {                               // emit cons row r0+j-2
            float4 vs;
            vs.x = w0.x+w1.x+w2.x; vs.y = w0.y+w1.y+w2.y;
            vs.z = w0.z+w1.z+w2.z; vs.w = w0.w+w1.w+w2.w;
            float L = __shfl_up(vs.w, 4);
            float R = __shfl_down(vs.x, 4);
            if (w4 == 0)  L = 0.f;
            if (w4 == 15) R = 0.f;
            float4 c;
            c.x = fabsf(L    + vs.x + vs.y);
            c.y = fabsf(vs.x + vs.y + vs.z);
            c.z = fabsf(vs.y + vs.z + vs.w);
            c.w = fabsf(vs.z + vs.w + R);
            c.x += __shfl_xor(c.x,1); c.x += __shfl_xor(c.x,2);
            c.y += __shfl_xor(c.y,1); c.y += __shfl_xor(c.y,2);
            c.z += __shfl_xor(c.z,1); c.z += __shfl_xor(c.z,2);
            c.w += __shfl_xor(c.w,1); c.w += __shfl_xor(c.w,2);
            if (pl == 0) consacc[v][j-2][w4] = c;
        }
    }

    // gw: reduce over pairs, stage per wave
    colacc.x += __shfl_xor(colacc.x,1); colacc.x += __shfl_xor(colacc.x,2);
    colacc.y += __shfl_xor(colacc.y,1); colacc.y += __shfl_xor(colacc.y,2);
    colacc.z += __shfl_xor(colacc.z,1); colacc.z += __shfl_xor(colacc.z,2);
    colacc.w += __shfl_xor(colacc.w,1); colacc.w += __shfl_xor(colacc.w,2);
    if (pl == 0) {
        gwacc[v][w4*4+0] = colacc.x;
        gwacc[v][w4*4+1] = colacc.y;
        gwacc[v][w4*4+2] = colacc.z;
        gwacc[v][w4*4+3] = colacc.w;
    }
    __syncthreads();   // the ONE barrier

    // ---- epilogue: cross-wave sums, plain stores
    const float SC  = 1.0f/(9.0f*128.0f);
    const float GSC = 1.0f/16384.0f;
    if (t < 128) {
        const int row = t >> 4, q = t & 15;
        const float4 s0 = consacc[0][row][q], s1 = consacc[1][row][q];
        const float4 s2 = consacc[2][row][q], s3 = consacc[3][row][q];
        float4 s;
        s.x = ((s0.x+s1.x)+(s2.x+s3.x))*SC;
        s.y = ((s0.y+s1.y)+(s2.y+s3.y))*SC;
        s.z = ((s0.z+s1.z)+(s2.z+s3.z))*SC;
        s.w = ((s0.w+s1.w)+(s2.w+s3.w))*SC;
        reinterpret_cast<float4*>(scr)[(cg << 14) + (b << 10) + (r0 + row)*16 + q] = s;
    } else if (t < 136) {
        const int row = t - 128;
        const float g = (ghacc[0][row]+ghacc[1][row])+(ghacc[2][row]+ghacc[3][row]);
        scr[SCR_GHP + (b*NH + r0 + row)*8 + cg] = g * GSC;
    } else if (t < 200) {
        const int w = t - 136;   // 0..63
        const float s = (gwacc[0][w]+gwacc[1][w])+(gwacc[2][w]+gwacc[3][w]);
        scr[SCR_GWP + (size_t)(b*NW + w)*64 + cg*8 + hg] = s * GSC;
    }
}

// 64 blocks (b, quarter): vectorized partial reductions, sum 8 cons slices,
// sigmoid -> att map in ws.
__global__ __launch_bounds__(256) void k_att(float* __restrict__ ws,
                                             const float* __restrict__ scr,
                                             const float* __restrict__ pgw,
                                             const float* __restrict__ pgb) {
    __shared__ __align__(16) float sgh[64];
    __shared__ __align__(16) float sgw[64];
    const int t = threadIdx.x;
    const int b = blockIdx.x >> 2;
    const int q = blockIdx.x & 3;

    if (t < 64) {
        const float4* gp = reinterpret_cast<const float4*>(scr + SCR_GWP + (size_t)(b*NW + t)*64);
        float acc = 0.f;
        #pragma unroll
        for (int i = 0; i < 16; ++i) acc += sum4(gp[i]);
        sgw[t] = acc;
    } else if (t < 128) {
        const int r = t - 64;
        const float4* gp = reinterpret_cast<const float4*>(scr + SCR_GHP + (b*NH + r)*8);
        sgh[r] = sum4(gp[0]) + sum4(gp[1]);
    }
    __syncthreads();

    const int u = (b << 10) + (q << 8) + t;   // float4-pixel 0..16383
    const float4* cp = reinterpret_cast<const float4*>(scr);
    float4 s = {0.f,0.f,0.f,0.f};
    #pragma unroll
    for (int g = 0; g < 8; ++g) {
        const float4 vv = cp[(g << 14) + u];
        s.x += vv.x; s.y += vv.y; s.z += vv.z; s.w += vv.w;
    }
    const int h  = (u >> 4) & 63;
    const int w4 = u & 15;
    const float ghv  = sgh[h];
    const float4 gwv = *reinterpret_cast<const float4*>(&sgw[w4*4]);
    const float gW = pgw[0], gB = pgb[0];

    float4 o;
    float z;
    z = gW*(ghv+gwv.x)*(1.f - fminf(fmaxf(s.x,0.f),1.f)) + gB; o.x = 1.f/(1.f+expf(-z));
    z = gW*(ghv+gwv.y)*(1.f - fminf(fmaxf(s.y,0.f),1.f)) + gB; o.y = 1.f/(1.f+expf(-z));
    z = gW*(ghv+gwv.z)*(1.f - fminf(fmaxf(s.z,0.f),1.f)) + gB; o.z = 1.f/(1.f+expf(-z));
    z = gW*(ghv+gwv.w)*(1.f - fminf(fmaxf(s.w,0.f),1.f)) + gB; o.w = 1.f/(1.f+expf(-z));
    reinterpret_cast<float4*>(ws + WS_ATT)[u] = o;
}

__global__ __launch_bounds__(256) void k_apply(const float* __restrict__ x,
                                               const float* __restrict__ ws,
                                               float* __restrict__ out) {
    const float* att = ws + WS_ATT;
    const int total4 = NB*NC*NH*NW/4;   // 4,194,304
    const int stride = gridDim.x * blockDim.x;
    for (int i = blockIdx.x*blockDim.x + threadIdx.x; i < total4; i += stride) {
        const int w4 = i & 15;
        const int h  = (i >> 4) & 63;
        const int b  = i >> 18;
        const float4 xv = reinterpret_cast<const float4*>(x)[i];
        const float4 av = reinterpret_cast<const float4*>(att)[(b << 10) + (h << 4) + w4];
        float4 o;
        o.x = xv.x*av.x; o.y = xv.y*av.y; o.z = xv.z*av.z; o.w = xv.w*av.w;
        reinterpret_cast<float4*>(out)[i] = o;
    }
}

extern "C" void kernel_launch(void* const* d_in, const int* in_sizes, int n_in,
                              void* d_out, int out_size, void* d_ws, size_t ws_size,
                              hipStream_t stream) {
    const float* x   = (const float*)d_in[0];
    const float* dwh = (const float*)d_in[1];
    const float* dww = (const float*)d_in[2];
    const float* pgw = (const float*)d_in[3];
    const float* pgb = (const float*)d_in[4];
    float* out = (float*)d_out;
    float* ws  = (float*)d_ws;
    // d_out doubles as scratch (~2.3 MB of partials): written by k_reduce,
    // consumed by k_att, then fully overwritten by k_apply.
    float* scr = out;

    k_reduce<<<NB*8*8, 256, 0, stream>>>(x, dwh, dww, scr);
    k_att<<<64, 256, 0, stream>>>(ws, scr, pgw, pgb);
    k_apply<<<2048, 256, 0, stream>>>(x, ws, out);
}